// Round 5
// baseline (1958.831 us; speedup 1.0000x reference)
//
#include <hip/hip_runtime.h>

#define EMBED   300
#define HIDDEN  256
#define SEQ     256
#define NG      1024          // 4*HIDDEN
#define NMAIN   32
#define CAP     (1 << 17)     // poll failsafe cap

typedef __attribute__((ext_vector_type(8))) short  short8;   // 8 bf16
typedef __attribute__((ext_vector_type(4))) float  f32x4;

__device__ inline unsigned short f2bf(float f) {
    unsigned u = __builtin_bit_cast(unsigned, f);
    return (unsigned short)((u + 0x7FFFu + ((u >> 16) & 1u)) >> 16);   // RNE
}
__device__ inline float bf2f(unsigned short h) {
    unsigned u = (unsigned)h << 16;
    return __builtin_bit_cast(float, u);
}
__device__ inline float sigm(float x)  { return 1.0f / (1.0f + __expf(-x)); }
__device__ inline float tanh_(float x) { return 2.0f / (1.0f + __expf(-2.0f * x)) - 1.0f; }
__device__ inline int swzb(int c, int base) { return base ^ (((c >> 1) & 3) << 4); }

// ---- relaxed agent-scope (LLC-coherent, per-XCD-L2 bypass) — round-3 proven ----
__device__ inline unsigned ld32a(const unsigned* p) {
    return __hip_atomic_load(p, __ATOMIC_RELAXED, __HIP_MEMORY_SCOPE_AGENT);
}
__device__ inline void st32a(unsigned* p, unsigned v) {
    __hip_atomic_store(p, v, __ATOMIC_RELAXED, __HIP_MEMORY_SCOPE_AGENT);
}
__device__ inline unsigned long long ld64a(const unsigned long long* p) {
    return __hip_atomic_load(p, __ATOMIC_RELAXED, __HIP_MEMORY_SCOPE_AGENT);
}
__device__ inline void st64a(unsigned long long* p, unsigned long long v) {
    __hip_atomic_store(p, v, __ATOMIC_RELAXED, __HIP_MEMORY_SCOPE_AGENT);
}
__device__ inline float ldf32a(const float* p) {
    return __builtin_bit_cast(float, ld32a((const unsigned*)p));
}
__device__ inline void stf32a(float* p, float v) {
    st32a((unsigned*)p, __builtin_bit_cast(unsigned, v));
}
__device__ inline short8 ldh16a(const unsigned short* p) {
    unsigned long long t0 = ld64a((const unsigned long long*)p);
    unsigned long long t1 = ld64a((const unsigned long long*)p + 1);
    union { unsigned long long q[2]; short8 s; } u;
    u.q[0] = t0; u.q[1] = t1;
    return u.s;
}

#define MFMA(a, b, c) __builtin_amdgcn_mfma_f32_16x16x32_bf16((a), (b), (c), 0, 0, 0)

// flags (u32 idx, 64B lines): f1 = lines 0..31, f2 = lines 32..63, hfl = lines 64..95
//   f1 = e+2  <=> main m published h1[e]      (init value 1 = zeros/setup done)
//   f2 = e+2  <=> main m finished epoch e (incl. gx1[e+1] prefetch)
//   hfl = t+1 <=> helper idx stored gx1[t]
__global__ __launch_bounds__(256, 1) void lstm_v5(
    const int*   __restrict__ xin,
    const float* __restrict__ emb,
    const float* __restrict__ W0, const float* __restrict__ b0,
    const float* __restrict__ W1, const float* __restrict__ b1,
    unsigned*       __restrict__ flags,
    unsigned short* __restrict__ h1,      // [2][64][256] bf16
    unsigned short* __restrict__ h2,      // [2][64][256] bf16
    float*          __restrict__ ring1,   // [4][64][1024] f32 (b0 folded)
    float*          __restrict__ out)     // [64][256] f32
{
    extern __shared__ char lds[];                 // 41984 B dynamic
    int* aliveP = (int*)(lds + 40960);
    const int tid = threadIdx.x, bid = blockIdx.x;
    const int w = tid >> 6, lane = tid & 63, l15 = lane & 15, q = lane >> 4;
    const int bbase = w * 16, arow = bbase + l15;
    bool alive = true;

    // =====================================================================
    if (bid < NMAIN) {                    // ---- fused main: L1rec + L2x + L2rec ----
        const int m = bid, u0 = m * 8;
        const int lo8 = l15 & 7;
        const bool gA = (l15 < 8);        // lane holds i/f gates (else j/o)

        // zero h1 slot1 (= h1[-1]) and h2 slots 0,1 for own stripe
        if (tid < 128) {
            int r = tid >> 1, p = tid & 1;
            st64a((unsigned long long*)(h1 + 16384 + r * 256 + u0) + p, 0ULL);
            st64a((unsigned long long*)(h2 +     0 + r * 256 + u0) + p, 0ULL);
            st64a((unsigned long long*)(h2 + 16384 + r * 256 + u0) + p, 0ULL);
        }

        // weight fragments, all in registers (cols: nt=0 -> i|j, nt=1 -> f|o)
        short8 bW0r[8][2], bW1x[8][2], bW1r[8][2];
        float biasx[2];
        #pragma unroll
        for (int nt = 0; nt < 2; ++nt) {
            int col = (2 * nt + (l15 >> 3)) * 256 + u0 + lo8;
            biasx[nt] = b1[col];
            #pragma unroll
            for (int s = 0; s < 8; ++s)
                #pragma unroll
                for (int e2 = 0; e2 < 8; ++e2) {
                    int k = s * 32 + q * 8 + e2;
                    bW0r[s][nt][e2] = (short)f2bf(W0[(long)(EMBED + k) * NG + col]);
                    bW1x[s][nt][e2] = (short)f2bf(W1[(long)k * NG + col]);
                    bW1r[s][nt][e2] = (short)f2bf(W1[(long)(HIDDEN + k) * NG + col]);
                }
        }
        asm volatile("s_waitcnt vmcnt(0)" ::: "memory");
        __syncthreads();
        if (tid == 0) { st32a(flags + m * 16, 1u); st32a(flags + (32 + m) * 16, 1u); }

        // init: wait helpers' gx1[0], prefetch it
        if (w == 0) {
            int n = 0;
            for (;;) {
                unsigned hv = (lane < 32) ? ld32a(flags + (64 + lane) * 16) : 0xFFFFFFFFu;
                if (__all(hv >= 1u)) break;
                if (++n > CAP) { alive = false; stf32a(out, 51000.f); break; }
            }
        }
        if (tid == 0) *aliveP = alive ? 1 : 0;
        __syncthreads();
        if (*aliveP == 0) return;

        f32x4 gn[2];
        #pragma unroll
        for (int nt = 0; nt < 2; ++nt) {
            int col = (2 * nt + (l15 >> 3)) * 256 + u0 + lo8;
            #pragma unroll
            for (int rr = 0; rr < 4; ++rr)
                gn[nt][rr] = ldf32a(ring1 + (size_t)(bbase + q * 4 + rr) * NG + col);
        }

        float c1[4] = {0.f, 0.f, 0.f, 0.f}, c2[4] = {0.f, 0.f, 0.f, 0.f};

        for (int e = 0; e <= 256; ++e) {
            // ---- combined epoch poll ----
            if (w == 0) {
                unsigned need = (lane < 32) ? (unsigned)(e + 1) : (unsigned)e;
                const unsigned* fp = flags + lane * 16;
                const bool nh = (e <= 254) && (lane < 32);
                const unsigned* hp = flags + (64 + lane) * 16;
                int n = 0;
                for (;;) {
                    unsigned v  = ld32a(fp);
                    unsigned hv = nh ? ld32a(hp) : 0xFFFFFFFFu;
                    if (__all((v >= need) && (hv >= (unsigned)(e + 2)))) break;
                    if (++n > CAP) { alive = false; stf32a(out, 50000.f + (float)e); break; }
                }
            }
            if (tid == 0) *aliveP = alive ? 1 : 0;
            __syncthreads();
            if (*aliveP == 0) break;

            // ---- reads (both h's issued together, before any publish) ----
            short8 a1[8], a2[8];
            {
                const unsigned short* p = h1 + ((e - 1) & 1) * 16384 + arow * 256;
                #pragma unroll
                for (int s = 0; s < 8; ++s) a1[s] = ldh16a(p + s * 32 + q * 8);
            }
            if (e >= 1) {
                const unsigned short* p = h2 + (e & 1) * 16384 + arow * 256;   // (e-2)&1 == e&1
                #pragma unroll
                for (int s = 0; s < 8; ++s) a2[s] = ldh16a(p + s * 32 + q * 8);
            }

            // ---- L2x: gacc = b1 + h1[e-1] @ W1x (reuses a1) ----
            f32x4 gacc[2];
            if (e >= 1) {
                #pragma unroll
                for (int nt = 0; nt < 2; ++nt)
                    gacc[nt] = (f32x4){biasx[nt], biasx[nt], biasx[nt], biasx[nt]};
                #pragma unroll
                for (int s = 0; s < 8; ++s)
                    #pragma unroll
                    for (int nt = 0; nt < 2; ++nt)
                        gacc[nt] = MFMA(a1[s], bW1x[s][nt], gacc[nt]);
            }

            // ---- L1rec + early h1 publish ----
            if (e <= 255) {
                f32x4 acc[2] = {gn[0], gn[1]};
                #pragma unroll
                for (int s = 0; s < 8; ++s)
                    #pragma unroll
                    for (int nt = 0; nt < 2; ++nt)
                        acc[nt] = MFMA(a1[s], bW0r[s][nt], acc[nt]);
                #pragma unroll
                for (int rr = 0; rr < 4; ++rr) {
                    float x0 = acc[0][rr], x1 = acc[1][rr];
                    float y0 = __shfl_xor(x0, 8), y1 = __shfl_xor(x1, 8);
                    float iv = gA ? x0 : y0, jv = gA ? y0 : x0;
                    float fv = gA ? x1 : y1, ov = gA ? y1 : x1;
                    float cn = c1[rr] * sigm(fv + 1.f) + sigm(iv) * tanh_(jv);
                    c1[rr] = cn;
                    float hn = tanh_(cn) * sigm(ov);
                    if (gA) *(unsigned short*)(lds + w * 256 + (q * 4 + rr) * 16 + lo8 * 2) = f2bf(hn);
                }
                asm volatile("s_waitcnt lgkmcnt(0)" ::: "memory");
                if (q == 0) {   // wave-local pack -> 16B agent store per row
                    unsigned long long v0 = *(unsigned long long*)(lds + w * 256 + l15 * 16);
                    unsigned long long v1 = *(unsigned long long*)(lds + w * 256 + l15 * 16 + 8);
                    unsigned long long* d = (unsigned long long*)(h1 + (e & 1) * 16384 + (bbase + l15) * 256 + u0);
                    st64a(d, v0); st64a(d + 1, v1);
                }
            }
            asm volatile("s_waitcnt vmcnt(0)" ::: "memory");
            __syncthreads();
            if (tid == 0 && e <= 255) st32a(flags + m * 16, (unsigned)(e + 2));

            // ---- prefetch gx1[e+1] (loads land under L2rec; drained before f2) ----
            if (e <= 254) {
                const float* g1 = ring1 + (size_t)((e + 1) & 3) * (64 * NG);
                #pragma unroll
                for (int nt = 0; nt < 2; ++nt) {
                    int col = (2 * nt + (l15 >> 3)) * 256 + u0 + lo8;
                    #pragma unroll
                    for (int rr = 0; rr < 4; ++rr)
                        gn[nt][rr] = ldf32a(g1 + (size_t)(bbase + q * 4 + rr) * NG + col);
                }
            }

            // ---- L2rec ----
            if (e >= 1) {
                f32x4 acc[2] = {gacc[0], gacc[1]};
                #pragma unroll
                for (int s = 0; s < 8; ++s)
                    #pragma unroll
                    for (int nt = 0; nt < 2; ++nt)
                        acc[nt] = MFMA(a2[s], bW1r[s][nt], acc[nt]);
                #pragma unroll
                for (int rr = 0; rr < 4; ++rr) {
                    float x0 = acc[0][rr], x1 = acc[1][rr];
                    float y0 = __shfl_xor(x0, 8), y1 = __shfl_xor(x1, 8);
                    float iv = gA ? x0 : y0, jv = gA ? y0 : x0;
                    float fv = gA ? x1 : y1, ov = gA ? y1 : x1;
                    float cn = c2[rr] * sigm(fv + 1.f) + sigm(iv) * tanh_(jv);
                    c2[rr] = cn;
                    float hn = tanh_(cn) * sigm(ov);
                    if (e == 256) {
                        if (gA) out[(bbase + q * 4 + rr) * 256 + u0 + lo8] = hn;
                    } else {
                        if (gA) *(unsigned short*)(lds + w * 256 + (q * 4 + rr) * 16 + lo8 * 2) = f2bf(hn);
                    }
                }
                if (e < 256) {
                    asm volatile("s_waitcnt lgkmcnt(0)" ::: "memory");
                    if (q == 0) {
                        unsigned long long v0 = *(unsigned long long*)(lds + w * 256 + l15 * 16);
                        unsigned long long v1 = *(unsigned long long*)(lds + w * 256 + l15 * 16 + 8);
                        unsigned long long* d = (unsigned long long*)(h2 + ((e - 1) & 1) * 16384 + (bbase + l15) * 256 + u0);
                        st64a(d, v0); st64a(d + 1, v1);
                    }
                }
            }
            asm volatile("s_waitcnt vmcnt(0)" ::: "memory");
            __syncthreads();
            if (tid == 0 && e < 256) st32a(flags + (32 + m) * 16, (unsigned)(e + 2));
        }

    // =====================================================================
    } else {                              // ---- gx1 helpers (round-3 proven) ----
        const int idx = bid - NMAIN;      // 0..31
        const int hc0 = idx * 32;
        float biasH[2];
        #pragma unroll
        for (int gi = 0; gi < 2; ++gi) biasH[gi] = b0[hc0 + gi * 16 + l15];
        for (int i2 = tid; i2 < 20 * 32 * 32; i2 += 256) {   // stage W0 x-part hi+lo
            int k = i2 >> 5, c = i2 & 31;
            int s = k >> 5, kk = k & 31;
            int row = (s >= 10) ? (k - 320) : k;
            float v = W0[(long)row * NG + hc0 + c];
            unsigned short hv = f2bf(v);
            if (s >= 10) hv = f2bf(v - bf2f(hv));
            *(unsigned short*)(lds + s * 2048 + swzb(c, c * 64 + kk * 2)) = hv;
        }
        __syncthreads();

        for (int t = 0; t <= 255; ++t) {
            // compute gx1[t]
            int xid = xin[arow * SEQ + t];
            const float* erow = emb + (long)xid * EMBED;
            short8 ac[10];
            #pragma unroll
            for (int s = 0; s < 10; ++s) {
                int kb = s * 32 + q * 8;
                #pragma unroll
                for (int hh = 0; hh < 2; ++hh) {
                    int k4 = kb + hh * 4;
                    if (k4 < EMBED) {
                        f32x4 v = *(const f32x4*)(erow + k4);
                        #pragma unroll
                        for (int e2 = 0; e2 < 4; ++e2) ac[s][hh * 4 + e2] = (short)f2bf(v[e2]);
                    } else {
                        #pragma unroll
                        for (int e2 = 0; e2 < 4; ++e2) ac[s][hh * 4 + e2] = 0;
                    }
                }
            }
            f32x4 accg[2];
            #pragma unroll
            for (int gi = 0; gi < 2; ++gi)
                accg[gi] = (f32x4){biasH[gi], biasH[gi], biasH[gi], biasH[gi]};
            #pragma unroll
            for (int s = 0; s < 20; ++s) {
                short8 a = ac[(s < 10) ? s : s - 10];
                #pragma unroll
                for (int gi = 0; gi < 2; ++gi) {
                    int c = gi * 16 + l15;
                    short8 b = *(const short8*)(lds + s * 2048 + swzb(c, c * 64 + q * 16));
                    accg[gi] = MFMA(a, b, accg[gi]);
                }
            }
            // back-pressure gate (ring depth 4): mains must have prefetched gx1[t-4]
            if (t >= 3) {
                unsigned need = (t - 3 < 2) ? 2u : (unsigned)(t - 3);
                if (w == 0) {
                    int n = 0;
                    for (;;) {
                        unsigned v = (lane < 32) ? ld32a(flags + (32 + lane) * 16) : 0xFFFFFFFFu;
                        if (__all(v >= need)) break;
                        if (++n > CAP) { alive = false; stf32a(out + 1, 60000.f + (float)t); break; }
                    }
                }
                if (tid == 0) *aliveP = alive ? 1 : 0;
                __syncthreads();
                if (*aliveP == 0) break;
            }
            // store + flag
            float* dst = ring1 + (size_t)(t & 3) * (64 * NG);
            #pragma unroll
            for (int gi = 0; gi < 2; ++gi)
                #pragma unroll
                for (int rr = 0; rr < 4; ++rr)
                    stf32a(dst + (size_t)(bbase + q * 4 + rr) * NG + hc0 + gi * 16 + l15, accg[gi][rr]);
            asm volatile("s_waitcnt vmcnt(0)" ::: "memory");
            __syncthreads();
            if (tid == 0) st32a(flags + (64 + idx) * 16, (unsigned)(t + 1));
        }
    }
}

__global__ void ws_too_small_sentinel(float* out, int n) {
    int i = blockIdx.x * 256 + threadIdx.x;
    if (i < n) out[i] = 31337.0f;
}

extern "C" void kernel_launch(void* const* d_in, const int* in_sizes, int n_in,
                              void* d_out, int out_size, void* d_ws, size_t ws_size,
                              hipStream_t stream)
{
    const int*   xin = (const int*)d_in[0];
    const float* emb = (const float*)d_in[1];
    const float* W0  = (const float*)d_in[2];
    const float* b0  = (const float*)d_in[3];
    const float* W1  = (const float*)d_in[4];
    const float* b1  = (const float*)d_in[5];
    float* out = (float*)d_out;

    const size_t OFF_FLAGS = 0;                       // 8 KB
    const size_t OFF_H1    = 8192;                    // 64 KB
    const size_t OFF_H2    = OFF_H1 + 65536;          // 64 KB
    const size_t OFF_RING1 = OFF_H2 + 65536;          // 1 MB
    const size_t NEED      = OFF_RING1 + (size_t)4 * 64 * NG * 4;   // 1,187,840 B

    if (ws_size < NEED) {   // diagnostic: absmax ~31337 => ws too small
        ws_too_small_sentinel<<<(out_size + 255) / 256, 256, 0, stream>>>(out, out_size);
        return;
    }

    char* ws = (char*)d_ws;
    unsigned*       flags = (unsigned*)(ws + OFF_FLAGS);
    unsigned short* h1    = (unsigned short*)(ws + OFF_H1);
    unsigned short* h2    = (unsigned short*)(ws + OFF_H2);
    float*          ring1 = (float*)(ws + OFF_RING1);

    hipMemsetAsync(flags, 0, 8192, stream);
    lstm_v5<<<dim3(64), dim3(256), 41984, stream>>>(
        xin, emb, W0, b0, W1, b1, flags, h1, h2, ring1, out);
}

// Round 7
// 1616.430 us; speedup vs baseline: 1.2118x; 1.2118x over previous
//
#include <hip/hip_runtime.h>

#define EMBED   300
#define HIDDEN  256
#define SEQ     256
#define NG      1024          // 4*HIDDEN
#define NL1     16
#define NL2     32
#define NBLK    112           // 16 L1 + 32 L2 + 64 helpers
#define CAP     (1 << 15)     // poll failsafe cap (~10ms, one-shot per block)

typedef __attribute__((ext_vector_type(8))) short  short8;   // 8 bf16
typedef __attribute__((ext_vector_type(4))) float  f32x4;
typedef unsigned long long ull;

__device__ inline unsigned short f2bf(float f) {
    unsigned u = __builtin_bit_cast(unsigned, f);
    return (unsigned short)((u + 0x7FFFu + ((u >> 16) & 1u)) >> 16);   // RNE
}
__device__ inline float bf2f(unsigned short h) {
    unsigned u = (unsigned)h << 16;
    return __builtin_bit_cast(float, u);
}
__device__ inline float sigm(float x)  { return 1.0f / (1.0f + __expf(-x)); }
__device__ inline float tanh_(float x) { return 2.0f / (1.0f + __expf(-2.0f * x)) - 1.0f; }
__device__ inline int swzb(int c, int base) { return base ^ (((c >> 1) & 3) << 4); }

// relaxed agent-scope (LLC-coherent, per-XCD-L2 bypass) — proven r3/r5
__device__ inline unsigned ld32a(const unsigned* p) {
    return __hip_atomic_load(p, __ATOMIC_RELAXED, __HIP_MEMORY_SCOPE_AGENT);
}
__device__ inline void st32a(unsigned* p, unsigned v) {
    __hip_atomic_store(p, v, __ATOMIC_RELAXED, __HIP_MEMORY_SCOPE_AGENT);
}
__device__ inline ull ld64a(const ull* p) {
    return __hip_atomic_load(p, __ATOMIC_RELAXED, __HIP_MEMORY_SCOPE_AGENT);
}
__device__ inline void st64a(ull* p, ull v) {
    __hip_atomic_store(p, v, __ATOMIC_RELAXED, __HIP_MEMORY_SCOPE_AGENT);
}
__device__ inline float ldf32a(const float* p) {
    return __builtin_bit_cast(float, ld32a((const unsigned*)p));
}
__device__ inline void stf32a(float* p, float v) {
    st32a((unsigned*)p, __builtin_bit_cast(unsigned, v));
}
__device__ inline short8 ldh16a(const unsigned short* p) {
    ull t0 = ld64a((const ull*)p);
    ull t1 = ld64a((const ull*)p + 1);
    union { ull q[2]; short8 s; } u;
    u.q[0] = t0; u.q[1] = t1;
    return u.s;
}

#define MFMA(a, b, c) __builtin_amdgcn_mfma_f32_16x16x32_bf16((a), (b), (c), 0, 0, 0)

// per-block monotone flag lines (u32 index; one flag per 64B line) — r5-proven
//   f1[i]  = e+2 after L1 block i published h1[e]   (1 = init done)
//   f2[i]  = t+2 after L2 block i finished step t    (1 = init done)
//   fh[p][s] = t+1 after helper (parity p, slice s) stored gx1[t]
#define F1(i)    ((i) * 16)
#define F2(i)    ((16 + (i)) * 16)
#define FH(p, s) ((48 + (p) * 32 + (s)) * 16)

__global__ __launch_bounds__(256, 1) void lstm_v7(
    const int*   __restrict__ xin,
    const float* __restrict__ emb,
    const float* __restrict__ W0, const float* __restrict__ b0,
    const float* __restrict__ W1, const float* __restrict__ b1,
    unsigned*       __restrict__ flags,
    unsigned short* __restrict__ h1,      // [4][64][256] bf16 ring
    unsigned short* __restrict__ h2,      // [2][64][256] bf16 ring
    float*          __restrict__ ring1,   // [4][64][1024] f32 (b0 folded)
    float*          __restrict__ out)     // [64][256] f32
{
    extern __shared__ char lds[];
    int* aliveP = (int*)(lds + 40960);
    const int tid = threadIdx.x, bid = blockIdx.x;
    const int w = tid >> 6, lane = tid & 63, l15 = lane & 15, q = lane >> 4;
    const int bbase = w * 16, arow = bbase + l15;
    bool alive = true;

    // wide poll: each w==0 lane watches up to two flag lines
    auto wpoll = [&](const unsigned* p0, unsigned t0,
                     const unsigned* p1, unsigned t1, float diag) -> bool {
        if (w == 0) {
            int n = 0;
            for (;;) {
                bool ok = ((p0 == nullptr) || (ld32a(p0) >= t0)) &&
                          ((p1 == nullptr) || (ld32a(p1) >= t1));
                if (__all(ok)) break;
                if (++n > CAP) { if (lane == 0) stf32a(out, diag); alive = false; break; }
            }
        }
        if (tid == 0) *aliveP = alive ? 1 : 0;
        __syncthreads();
        return *aliveP != 0;
    };
    auto drain_sync = [&]() {
        asm volatile("s_waitcnt vmcnt(0)" ::: "memory");
        __syncthreads();
    };

    // =====================================================================
    if (bid < NL1) {                       // ---- L1 recurrence (16-unit stripes) ----
        const int u0 = bid * 16;
        { int r = tid >> 2, p = tid & 3;   // zero h1[-1] (slot 3), own stripe
          st64a((ull*)(h1 + 3 * 16384 + r * 256 + u0) + p, 0ULL); }
        short8 bfragR[8][4];
        #pragma unroll
        for (int s = 0; s < 8; ++s)
            #pragma unroll
            for (int nt = 0; nt < 4; ++nt)
                #pragma unroll
                for (int e2 = 0; e2 < 8; ++e2) {
                    int k = EMBED + s * 32 + q * 8 + e2;
                    bfragR[s][nt][e2] = (short)f2bf(W0[(long)k * NG + nt * 256 + u0 + l15]);
                }
        drain_sync();
        if (tid == 0) st32a(flags + F1(bid), 1u);

        {   // pre-loop: gx1[0] present (parity-0 helpers)
            const unsigned* p0 = (lane < 32) ? flags + FH(0, lane) : nullptr;
            if (!wpoll(p0, 1u, nullptr, 0u, 52000.f)) return;
        }
        f32x4 gn[4];                        // prefetch gx1[0]
        #pragma unroll
        for (int nt = 0; nt < 4; ++nt)
            #pragma unroll
            for (int rr = 0; rr < 4; ++rr)
                gn[nt][rr] = ldf32a(ring1 + (size_t)(bbase + q * 4 + rr) * NG + nt * 256 + u0 + l15);

        float c4[4] = {0.f, 0.f, 0.f, 0.f};
        for (int e = 0; e <= 255; ++e) {
            // single poll: h1[e-1] published; L2 done t=e-4 (slot free); gx1[e+1] stored
            const unsigned* p0 = nullptr; unsigned t0 = 0;
            if (lane < 16) { p0 = flags + F1(lane); t0 = (unsigned)(e + 1); }
            else if (lane < 48 && e >= 4) { p0 = flags + F2(lane - 16); t0 = (unsigned)(e - 2); }
            const unsigned* p1 = (e <= 254 && lane < 32) ? flags + FH((e + 1) & 1, lane) : nullptr;
            if (!wpoll(p0, t0, p1, (unsigned)(e + 2), 51000.f + (float)e)) break;

            short8 a1[8];
            { const unsigned short* hb = h1 + ((e - 1) & 3) * 16384 + arow * 256;
              #pragma unroll
              for (int s = 0; s < 8; ++s) a1[s] = ldh16a(hb + s * 32 + q * 8); }

            f32x4 acc[4] = {gn[0], gn[1], gn[2], gn[3]};
            #pragma unroll
            for (int s = 0; s < 8; ++s)
                #pragma unroll
                for (int nt = 0; nt < 4; ++nt)
                    acc[nt] = MFMA(a1[s], bfragR[s][nt], acc[nt]);

            #pragma unroll
            for (int rr = 0; rr < 4; ++rr) {
                int b = bbase + q * 4 + rr;
                float iv = sigm(acc[0][rr]);
                float jv = tanh_(acc[1][rr]);
                float fv = sigm(acc[2][rr] + 1.0f);
                float ov = sigm(acc[3][rr]);
                float cn = c4[rr] * fv + iv * jv;
                c4[rr] = cn;
                *(unsigned short*)(lds + b * 32 + l15 * 2) = f2bf(tanh_(cn) * ov);
            }
            asm volatile("s_waitcnt lgkmcnt(0)" ::: "memory");
            {   // wave-local repack publish: row bbase+(lane>>2), u64 part lane&3
                int r = bbase + (lane >> 2), p = lane & 3;
                ull v = *(ull*)(lds + r * 32 + p * 8);
                st64a((ull*)(h1 + (e & 3) * 16384 + r * 256 + u0) + p, v);
            }
            drain_sync();
            if (tid == 0) st32a(flags + F1(bid), (unsigned)(e + 2));

            if (e <= 254) {                 // prefetch gx1[e+1] (availability already polled)
                const float* g1 = ring1 + (size_t)((e + 1) & 3) * (64 * NG);
                #pragma unroll
                for (int nt = 0; nt < 4; ++nt)
                    #pragma unroll
                    for (int rr = 0; rr < 4; ++rr)
                        gn[nt][rr] = ldf32a(g1 + (size_t)(bbase + q * 4 + rr) * NG + nt * 256 + u0 + l15);
            }
        }

    // =====================================================================
    } else if (bid < NL1 + NL2) {          // ---- L2 fused x-part + recurrence ----
        const int idx = bid - NL1, u0 = idx * 8;
        const int lo8 = l15 & 7;
        const bool gA = (l15 < 8);
        if (tid < 128) {                   // zero h2[-1] (slot 1), own stripe
            int r = tid >> 1, p = tid & 1;
            st64a((ull*)(h2 + 16384 + r * 256 + u0) + p, 0ULL);
        }
        short8 bW1x[8][2], bW1r[8][2];
        float biasx[2];
        #pragma unroll
        for (int nt = 0; nt < 2; ++nt) {
            int col = (2 * nt + (l15 >> 3)) * 256 + u0 + lo8;
            biasx[nt] = b1[col];
            #pragma unroll
            for (int s = 0; s < 8; ++s)
                #pragma unroll
                for (int e2 = 0; e2 < 8; ++e2) {
                    int k = s * 32 + q * 8 + e2;
                    bW1x[s][nt][e2] = (short)f2bf(W1[(long)k * NG + col]);
                    bW1r[s][nt][e2] = (short)f2bf(W1[(long)(HIDDEN + k) * NG + col]);
                }
        }
        drain_sync();
        if (tid == 0) st32a(flags + F2(idx), 1u);

        float c4[4] = {0.f, 0.f, 0.f, 0.f};
        for (int t = 0; t <= 255; ++t) {
            // poll: h1[t] published by all L1; all L2 finished t-1 (h2 ready + slot free)
            const unsigned* p0 = nullptr; unsigned t0 = 0;
            if (lane < 16) { p0 = flags + F1(lane); t0 = (unsigned)(t + 2); }
            else if (lane < 48) { p0 = flags + F2(lane - 16); t0 = (unsigned)(t + 1); }
            if (!wpoll(p0, t0, nullptr, 0u, 54000.f + (float)t)) break;

            short8 a1[8], a2[8];
            const unsigned short* b1p = h1 + (t & 3) * 16384 + arow * 256;
            const unsigned short* b2p = h2 + ((t - 1) & 1) * 16384 + arow * 256;
            #pragma unroll
            for (int s = 0; s < 8; ++s) {
                a1[s] = ldh16a(b1p + s * 32 + q * 8);
                a2[s] = ldh16a(b2p + s * 32 + q * 8);
            }

            f32x4 acc[2] = { (f32x4){biasx[0], biasx[0], biasx[0], biasx[0]},
                             (f32x4){biasx[1], biasx[1], biasx[1], biasx[1]} };
            #pragma unroll
            for (int s = 0; s < 8; ++s)
                #pragma unroll
                for (int nt = 0; nt < 2; ++nt)
                    acc[nt] = MFMA(a1[s], bW1x[s][nt], acc[nt]);
            #pragma unroll
            for (int s = 0; s < 8; ++s)
                #pragma unroll
                for (int nt = 0; nt < 2; ++nt)
                    acc[nt] = MFMA(a2[s], bW1r[s][nt], acc[nt]);

            #pragma unroll
            for (int rr = 0; rr < 4; ++rr) {
                float x0 = acc[0][rr], x1 = acc[1][rr];
                float y0 = __shfl_xor(x0, 8), y1 = __shfl_xor(x1, 8);
                float iv = gA ? x0 : y0, jv = gA ? y0 : x0;
                float fv = gA ? x1 : y1, ov = gA ? y1 : x1;
                float cn = c4[rr] * sigm(fv + 1.f) + sigm(iv) * tanh_(jv);
                c4[rr] = cn;
                float hn = tanh_(cn) * sigm(ov);
                if (t == 255) {
                    if (gA) out[(bbase + q * 4 + rr) * 256 + u0 + lo8] = hn;
                } else {
                    if (gA) *(unsigned short*)(lds + w * 256 + (q * 4 + rr) * 16 + lo8 * 2) = f2bf(hn);
                }
            }
            if (t == 255) break;
            asm volatile("s_waitcnt lgkmcnt(0)" ::: "memory");
            if (q == 0) {                  // wave-local publish: 16B per row
                ull v0 = *(ull*)(lds + w * 256 + l15 * 16);
                ull v1 = *(ull*)(lds + w * 256 + l15 * 16 + 8);
                ull* d = (ull*)(h2 + (t & 1) * 16384 + (bbase + l15) * 256 + u0);
                st64a(d, v0); st64a(d + 1, v1);
            }
            drain_sync();
            if (tid == 0) st32a(flags + F2(idx), (unsigned)(t + 2));
        }

    // =====================================================================
    } else {                               // ---- gx1 helpers (parity x 32 slices) ----
        const int hidx = bid - NL1 - NL2;  // 0..63
        const int par = hidx & 1, slice = hidx >> 1, hc0 = slice * 32;
        float biasH[2];
        #pragma unroll
        for (int gi = 0; gi < 2; ++gi) biasH[gi] = b0[hc0 + gi * 16 + l15];
        for (int i2 = tid; i2 < 20 * 32 * 32; i2 += 256) {   // W0 x-part hi+lo residual
            int k = i2 >> 5, c = i2 & 31;
            int s = k >> 5, kk = k & 31;
            int row = (s >= 10) ? (k - 320) : k;
            float v = W0[(long)row * NG + hc0 + c];
            unsigned short hv = f2bf(v);
            if (s >= 10) hv = f2bf(v - bf2f(hv));
            *(unsigned short*)(lds + s * 2048 + swzb(c, c * 64 + kk * 2)) = hv;
        }
        __syncthreads();

        for (int t = par; t <= 255; t += 2) {
            int xid = xin[arow * SEQ + t];
            const float* erow = emb + (long)xid * EMBED;
            short8 ac[10];
            #pragma unroll
            for (int s = 0; s < 10; ++s) {
                int kb = s * 32 + q * 8;
                #pragma unroll
                for (int hh = 0; hh < 2; ++hh) {
                    int k4 = kb + hh * 4;
                    if (k4 < EMBED) {
                        f32x4 v = *(const f32x4*)(erow + k4);
                        #pragma unroll
                        for (int e2 = 0; e2 < 4; ++e2) ac[s][hh * 4 + e2] = (short)f2bf(v[e2]);
                    } else {
                        #pragma unroll
                        for (int e2 = 0; e2 < 4; ++e2) ac[s][hh * 4 + e2] = 0;
                    }
                }
            }
            f32x4 accg[2];
            #pragma unroll
            for (int gi = 0; gi < 2; ++gi)
                accg[gi] = (f32x4){biasH[gi], biasH[gi], biasH[gi], biasH[gi]};
            #pragma unroll
            for (int s = 0; s < 20; ++s) {
                short8 a = ac[(s < 10) ? s : s - 10];
                #pragma unroll
                for (int gi = 0; gi < 2; ++gi) {
                    int c = gi * 16 + l15;
                    short8 b = *(const short8*)(lds + s * 2048 + swzb(c, c * 64 + q * 16));
                    accg[gi] = MFMA(a, b, accg[gi]);
                }
            }
            // slot gate: all L1 set f1 >= t-2 (their gx1[t-4] prefetch loads drained)
            if (t >= 4) {
                const unsigned* p0 = (lane < 16) ? flags + F1(lane) : nullptr;
                if (!wpoll(p0, (unsigned)(t - 2), nullptr, 0u, 55000.f + (float)t)) break;
            }
            float* dst = ring1 + (size_t)(t & 3) * (64 * NG);
            #pragma unroll
            for (int gi = 0; gi < 2; ++gi)
                #pragma unroll
                for (int rr = 0; rr < 4; ++rr)
                    stf32a(dst + (size_t)(bbase + q * 4 + rr) * NG + hc0 + gi * 16 + l15, accg[gi][rr]);
            drain_sync();
            if (tid == 0) st32a(flags + FH(par, slice), (unsigned)(t + 1));
        }
    }
}

__global__ void ws_too_small_sentinel(float* out, int n) {
    int i = blockIdx.x * 256 + threadIdx.x;
    if (i < n) out[i] = 31337.0f;
}

extern "C" void kernel_launch(void* const* d_in, const int* in_sizes, int n_in,
                              void* d_out, int out_size, void* d_ws, size_t ws_size,
                              hipStream_t stream)
{
    const int*   xin = (const int*)d_in[0];
    const float* emb = (const float*)d_in[1];
    const float* W0  = (const float*)d_in[2];
    const float* b0  = (const float*)d_in[3];
    const float* W1  = (const float*)d_in[4];
    const float* b1  = (const float*)d_in[5];
    float* out = (float*)d_out;

    const size_t OFF_FLAGS = 0;                           // 8 KB (112 flag lines)
    const size_t OFF_H1    = 8192;                        // 128 KB (depth 4)
    const size_t OFF_H2    = OFF_H1 + 131072;             // 64 KB (depth 2)
    const size_t OFF_RING1 = OFF_H2 + 65536;              // 1 MB (depth 4)
    const size_t NEED      = OFF_RING1 + (size_t)4 * 64 * NG * 4;   // 1,253,376 B (< proven 1,589,248)

    if (ws_size < NEED) {   // diagnostic: absmax ~31337 => ws too small
        ws_too_small_sentinel<<<(out_size + 255) / 256, 256, 0, stream>>>(out, out_size);
        return;
    }

    char* ws = (char*)d_ws;
    unsigned*       flags = (unsigned*)(ws + OFF_FLAGS);
    unsigned short* h1    = (unsigned short*)(ws + OFF_H1);
    unsigned short* h2    = (unsigned short*)(ws + OFF_H2);
    float*          ring1 = (float*)(ws + OFF_RING1);

    hipMemsetAsync(flags, 0, 8192, stream);
    lstm_v7<<<dim3(NBLK), dim3(256), 41088, stream>>>(
        xin, emb, W0, b0, W1, b1, flags, h1, h2, ring1, out);
}